// Round 9
// baseline (116.101 us; speedup 1.0000x reference)
//
#include <hip/hip_runtime.h>

// Problem constants (fixed by the reference module)
#define B_ 16
#define L_ 2048
#define D_ 128
#define GROUP_ 16
#define NG_ (L_ / GROUP_)   // 128
#define LOG2E_ 1.44269504088896340736f

// DPP-based butterfly add within each 16-lane row (full-rate VALU, no LDS).
template<int CTRL>
__device__ __forceinline__ float dpp_add(float v) {
    int x = __builtin_amdgcn_update_dpp(0, __float_as_int(v), CTRL, 0xF, 0xF, false);
    return v + __int_as_float(x);
}
__device__ __forceinline__ float row16_sum(float v) {
    v = dpp_add<0xB1>(v);   // quad_perm(1,0,3,2)  ~ xor 1
    v = dpp_add<0x4E>(v);   // quad_perm(2,3,0,1)  ~ xor 2
    v = dpp_add<0x141>(v);  // row_half_mirror     ~ xor 4
    v = dpp_add<0x140>(v);  // row_mirror          ~ xor 8
    return v;
}

// lgkm-only barrier (no vmcnt drain on the 16-step critical path).
#define LGKM_BARRIER() asm volatile("s_waitcnt lgkmcnt(0)\n\ts_barrier" ::: "memory")

// R18 = R17 structure, hot loop fully SCALARIZED.
// Evidence: per-SIMD issue is 2-2.5x the source op count in every round
// (R9: 550 cyc/wave-step vs ~180 source; R17: 955 vs ~480), VGPR_Count
// always below the declared live set (44/28/60/64), and R11 proved the
// bound pipe is VALU-issue (added VALU -> proportional regression; trans
// swaps ~free). Common factor: v2 ext-vector plumbing - 4 pair<->scalar
// crossings per element (pk fma -> scalar exp/rcp -> pk -> scalar), sim
// splats, float4->v2 repacks; each crossing risks v_mov pairs and the
// pairing constraints plausibly drive the chronic demotion. Fix: plain
// scalar floats everywhere in the loop (no pairing constraints at all);
// float4 only at LDS/global load-store boundaries (subreg access free).
// waves_per_eu(2,4): 256-VGPR budget (occupancy proven insensitive).
//
// Per-element update (identical arithmetic to R14/R17, scalar form):
#define UPD1(CXI, ZA, SIM, XJ, K, SELFN)                                      \
    {                                                                         \
        float u  = __builtin_fmaf(SIM, XJ, CXI);                              \
        float r1 = __builtin_amdgcn_rcpf(__builtin_amdgcn_exp2f(u) + 1.0f);   \
        float tn = __builtin_fmaf(G1S[K], r1, B1S[K]);                        \
        float fv = SELFN(tn, tn * 0.01f);                                     \
        ZA += fv;                                                             \
        float r2 = __builtin_amdgcn_rcpf(__builtin_amdgcn_exp2f(ZA) + 1.0f);  \
        CXI = __builtin_fmaf(G2c[K], r2, CXI + B2c[K]);                       \
    }

#define STEP_LOOP(SELFN)                                                      \
    for (int j = 0; j < GROUP_; ++j) {                                        \
        const int p = j & 1;                                                  \
        float xj[8];                                                          \
        {                                                                     \
            float4 tA = *(const float4*)&s_xj[p][d0];                         \
            float4 tB = *(const float4*)&s_xj[p][d0 + 4];                     \
            xj[0] = tA.x; xj[1] = tA.y; xj[2] = tA.z; xj[3] = tA.w;           \
            xj[4] = tB.x; xj[5] = tB.y; xj[6] = tB.z; xj[7] = tB.w;           \
        }                                                                     \
        /* shared xj-dot partial, then per-row partials (all scalar fma) */   \
        float pj = 0.0f, svA, svB;                                            \
        _Pragma("unroll")                                                     \
        for (int k = 0; k < 8; ++k) pj = __builtin_fmaf(xj[k], Wj[k], pj);    \
        svA = pj; svB = pj;                                                   \
        _Pragma("unroll")                                                     \
        for (int k = 0; k < 8; ++k) svA = __builtin_fmaf(cxiA[k], Wi[k], svA);\
        _Pragma("unroll")                                                     \
        for (int k = 0; k < 8; ++k) svB = __builtin_fmaf(cxiB[k], Wi[k], svB);\
        const float simA = row16_sum(svA);                                    \
        const float simB = row16_sum(svB);                                    \
        _Pragma("unroll")                                                     \
        for (int k = 0; k < 8; ++k) UPD1(cxiA[k], zaA[k], simA, xj[k], k, SELFN) \
        _Pragma("unroll")                                                     \
        for (int k = 0; k < 8; ++k) UPD1(cxiB[k], zaB[k], simB, xj[k], k, SELFN) \
        const int jn = j + 1;                                                 \
        if (jn < GROUP_ && rp == (jn & 7)) {                                  \
            if (jn & 8) {                                                     \
                float4 oA = {cxiB[0], cxiB[1], cxiB[2], cxiB[3]};             \
                float4 oB = {cxiB[4], cxiB[5], cxiB[6], cxiB[7]};             \
                *(float4*)&s_xj[p ^ 1][d0]     = oA;                          \
                *(float4*)&s_xj[p ^ 1][d0 + 4] = oB;                          \
            } else {                                                          \
                float4 oA = {cxiA[0], cxiA[1], cxiA[2], cxiA[3]};             \
                float4 oB = {cxiA[4], cxiA[5], cxiA[6], cxiA[7]};             \
                *(float4*)&s_xj[p ^ 1][d0]     = oA;                          \
                *(float4*)&s_xj[p ^ 1][d0 + 4] = oB;                          \
            }                                                                 \
        }                                                                     \
        LGKM_BARRIER();                                                       \
    }

__global__ __launch_bounds__(128)
__attribute__((amdgpu_waves_per_eu(2, 4)))
void ncn_kernel(
    const float* __restrict__ x,       // (B, L, D)
    const int*   __restrict__ gt,      // (B, L) permutation
    const int*   __restrict__ ctxlens, // (B,)
    const float* __restrict__ W,       // (2D,)
    const float* __restrict__ nalpha,  // (2,)
    const float* __restrict__ ngamma,  // (2D,)
    const float* __restrict__ nbeta,   // (2D,)
    float* __restrict__ out)           // (2, B, L, D) concat: yi_out, ya_out
{
    const int blk = blockIdx.x;
    const int b   = blk >> 7;      // / NG_
    const int g   = blk & (NG_ - 1);
    const int tid = threadIdx.x;   // 0..127
    const int rp  = tid >> 4;      // 0..7 (row pair: owns rows rp and rp+8)
    const int rl  = tid & 15;      // 0..15 (lane within row)
    const int d0  = rl << 3;       // 8 d-elements per thread

    __shared__ float s_xj[2][D_];  // double-buffered broadcast row (holds cxj)

    const float a1 = nalpha[0];
    const float a2 = nalpha[1];
    const float ca = -a1 * LOG2E_;        // u = ca*(xi + sim*xj); ALPHA=0.5 folded
    const float S  = -2.0f * a2 * LOG2E_; // za = S*xa, so exp2(za) direct
    const float inv_ca = 1.0f / ca;
    const bool  selMin = (S < 0.0f);      // leaky-relu under sign flip

    // Per-thread constants (reused 16x), all scalar. Wi,Wj pre-scaled by
    // 1/ca (sim computed from cxi); G2c,B2c pre-scaled by ca.
    float Wi[8], Wj[8], G1S[8], B1S[8], G2c[8], B2c[8];
    {
        float4 wA = *(const float4*)(W + d0);
        float4 wB = *(const float4*)(W + d0 + 4);
        float4 vA = *(const float4*)(W + D_ + d0);
        float4 vB = *(const float4*)(W + D_ + d0 + 4);
        Wi[0]=wA.x*inv_ca; Wi[1]=wA.y*inv_ca; Wi[2]=wA.z*inv_ca; Wi[3]=wA.w*inv_ca;
        Wi[4]=wB.x*inv_ca; Wi[5]=wB.y*inv_ca; Wi[6]=wB.z*inv_ca; Wi[7]=wB.w*inv_ca;
        Wj[0]=vA.x*inv_ca; Wj[1]=vA.y*inv_ca; Wj[2]=vA.z*inv_ca; Wj[3]=vA.w*inv_ca;
        Wj[4]=vB.x*inv_ca; Wj[5]=vB.y*inv_ca; Wj[6]=vB.z*inv_ca; Wj[7]=vB.w*inv_ca;

        float4 g1A = *(const float4*)(ngamma + d0);
        float4 g1B = *(const float4*)(ngamma + d0 + 4);
        float4 g2A = *(const float4*)(ngamma + D_ + d0);
        float4 g2B = *(const float4*)(ngamma + D_ + d0 + 4);
        float4 b1A = *(const float4*)(nbeta + d0);
        float4 b1B = *(const float4*)(nbeta + d0 + 4);
        float4 b2A = *(const float4*)(nbeta + D_ + d0);
        float4 b2B = *(const float4*)(nbeta + D_ + d0 + 4);

        float g1[8] = {g1A.x,g1A.y,g1A.z,g1A.w,g1B.x,g1B.y,g1B.z,g1B.w};
        float b1[8] = {b1A.x,b1A.y,b1A.z,b1A.w,b1B.x,b1B.y,b1B.z,b1B.w};
        float g2[8] = {g2A.x,g2A.y,g2A.z,g2A.w,g2B.x,g2B.y,g2B.z,g2B.w};
        float b2[8] = {b2A.x,b2A.y,b2A.z,b2A.w,b2B.x,b2B.y,b2B.z,b2B.w};
#pragma unroll
        for (int k = 0; k < 8; ++k) {
            G1S[k] = (S * 2.0f) * g1[k];      // S*(2*g1)
            B1S[k] = S * (b1[k] - g1[k]);     // S*(b1-g1)
            G2c[k] = (ca * 2.0f) * g2[k];     // ca*(2*g2)
            B2c[k] = ca * (b2[k] - g2[k]);    // ca*(b2-g2)
        }
    }

    // Tokens + gather for BOTH owned rows; state is cxi = ca * xi (scalar).
    const int lA   = g * GROUP_ + rp;
    const int tokA = gt[b * L_ + lA];
    const int tokB = gt[b * L_ + lA + 8];
    const float* xpA = x + ((size_t)(b * L_ + tokA)) * D_ + d0;
    const float* xpB = x + ((size_t)(b * L_ + tokB)) * D_ + d0;

    float cxiA[8], zaA[8], cxiB[8], zaB[8];
    {
        float4 xA = *(const float4*)xpA;
        float4 xB = *(const float4*)(xpA + 4);
        cxiA[0]=xA.x*ca; cxiA[1]=xA.y*ca; cxiA[2]=xA.z*ca; cxiA[3]=xA.w*ca;
        cxiA[4]=xB.x*ca; cxiA[5]=xB.y*ca; cxiA[6]=xB.z*ca; cxiA[7]=xB.w*ca;
        float4 yA = *(const float4*)xpB;
        float4 yB = *(const float4*)(xpB + 4);
        cxiB[0]=yA.x*ca; cxiB[1]=yA.y*ca; cxiB[2]=yA.z*ca; cxiB[3]=yA.w*ca;
        cxiB[4]=yB.x*ca; cxiB[5]=yB.y*ca; cxiB[6]=yB.z*ca; cxiB[7]=yB.w*ca;
    }
#pragma unroll
    for (int k = 0; k < 8; ++k) { zaA[k] = 0.0f; zaB[k] = 0.0f; }

    // Row 0 (pair 0, sub-row A) publishes its initial cxi into buffer 0
    if (rp == 0) {
        float4 oA = {cxiA[0], cxiA[1], cxiA[2], cxiA[3]};
        float4 oB = {cxiA[4], cxiA[5], cxiA[6], cxiA[7]};
        *(float4*)&s_xj[0][d0]     = oA;
        *(float4*)&s_xj[0][d0 + 4] = oB;
    }
    __syncthreads();

    // Uniform split: one v_min / v_max per elem.
    if (selMin) {
        STEP_LOOP(__builtin_fminf)
    } else {
        STEP_LOOP(__builtin_fmaxf)
    }

    // Recover xi = cxi / ca and xa = za / S; scatter both rows.
    const float invS = 1.0f / S;

    const bool valid = (g * GROUP_) < ctxlens[b];
    const float mA = valid ? inv_ca : 0.0f;   // fold zeroing into the unscale
    const float mS = valid ? invS   : 0.0f;

    float* o1A = out + ((size_t)(b * L_ + tokA)) * D_ + d0;
    float* o1B = out + ((size_t)(b * L_ + tokB)) * D_ + d0;
    float* o2A = o1A + (size_t)B_ * L_ * D_;
    float* o2B = o1B + (size_t)B_ * L_ * D_;

    float4 s1A = {cxiA[0]*mA, cxiA[1]*mA, cxiA[2]*mA, cxiA[3]*mA};
    float4 s1B = {cxiA[4]*mA, cxiA[5]*mA, cxiA[6]*mA, cxiA[7]*mA};
    float4 s2A = {zaA[0]*mS,  zaA[1]*mS,  zaA[2]*mS,  zaA[3]*mS};
    float4 s2B = {zaA[4]*mS,  zaA[5]*mS,  zaA[6]*mS,  zaA[7]*mS};
    *(float4*)o1A       = s1A;
    *(float4*)(o1A + 4) = s1B;
    *(float4*)o2A       = s2A;
    *(float4*)(o2A + 4) = s2B;

    float4 t1A = {cxiB[0]*mA, cxiB[1]*mA, cxiB[2]*mA, cxiB[3]*mA};
    float4 t1B = {cxiB[4]*mA, cxiB[5]*mA, cxiB[6]*mA, cxiB[7]*mA};
    float4 t2A = {zaB[0]*mS,  zaB[1]*mS,  zaB[2]*mS,  zaB[3]*mS};
    float4 t2B = {zaB[4]*mS,  zaB[5]*mS,  zaB[6]*mS,  zaB[7]*mS};
    *(float4*)o1B       = t1A;
    *(float4*)(o1B + 4) = t1B;
    *(float4*)o2B       = t2A;
    *(float4*)(o2B + 4) = t2B;
}

extern "C" void kernel_launch(void* const* d_in, const int* in_sizes, int n_in,
                              void* d_out, int out_size, void* d_ws, size_t ws_size,
                              hipStream_t stream) {
    const float* x  = (const float*)d_in[0];
    const int*   gt = (const int*)d_in[1];
    const int*   cl = (const int*)d_in[2];
    const float* W  = (const float*)d_in[3];
    const float* na = (const float*)d_in[4];
    const float* ng = (const float*)d_in[5];
    const float* nb = (const float*)d_in[6];
    float* out = (float*)d_out;

    ncn_kernel<<<B_ * NG_, 128, 0, stream>>>(x, gt, cl, W, na, ng, nb, out);
}

// Round 10
// 113.516 us; speedup vs baseline: 1.0228x; 1.0228x over previous
//
#include <hip/hip_runtime.h>

// Problem constants (fixed by the reference module)
#define B_ 16
#define L_ 2048
#define D_ 128
#define GROUP_ 16
#define NG_ (L_ / GROUP_)   // 128
#define LOG2E_ 1.44269504088896340736f

typedef float v2 __attribute__((ext_vector_type(2)));

// DPP-based butterfly add within each 16-lane row (full-rate VALU, no LDS).
template<int CTRL>
__device__ __forceinline__ float dpp_add(float v) {
    int x = __builtin_amdgcn_update_dpp(0, __float_as_int(v), CTRL, 0xF, 0xF, false);
    return v + __int_as_float(x);
}
__device__ __forceinline__ float row16_sum(float v) {
    v = dpp_add<0xB1>(v);   // quad_perm(1,0,3,2)  ~ xor 1
    v = dpp_add<0x4E>(v);   // quad_perm(2,3,0,1)  ~ xor 2
    v = dpp_add<0x141>(v);  // row_half_mirror     ~ xor 4
    v = dpp_add<0x140>(v);  // row_mirror          ~ xor 8
    return v;
}

// lgkm-only barrier (no vmcnt drain on the 16-step critical path).
#define LGKM_BARRIER() asm volatile("s_waitcnt lgkmcnt(0)\n\ts_barrier" ::: "memory")

// R19: TWO GROUPS PER BLOCK. Evidence: per-step wall ~3400 cyc vs ~1100
// busy across all configs -> serial-chain latency (ds_read -> 24-deep fma
// -> DPP reduce -> exp/rcp chains -> publish) unhidden at 2-4 waves/SIMD,
// paid once per barrier; R9->R17 showed the work-per-barrier axis responds.
// Thread (row, rl) owns row `row` of BOTH groups (8 dims each): per step
// ONE barrier covers 2 groups' steps (barrier count halved per work);
// A/B chains interleave for 2x ILP in every latency window; grid = 1024
// blocks = exactly 4 blocks/CU -> whole problem resident in ONE pass.
// Constants shared across groups (+16 state regs vs R17, same budget
// class). Math bit-identical to R14/R16 (absmax 0.125).
//
// Per-element update (R14's chain): u=fma; r=rcp(exp2+1); tn=fma; leaky
// via one min/max; za+=; r2; cxi=fma. SELFN = min (S<0) or max.
#define UPD8(CXI, ZA, SIMV, XJV, SELFN)                                       \
    _Pragma("unroll")                                                         \
    for (int k = 0; k < 4; ++k) {                                             \
        v2 u  = __builtin_elementwise_fma(SIMV, XJV[k], CXI[k]);              \
        v2 r1 = (v2){__builtin_amdgcn_rcpf(__builtin_amdgcn_exp2f(u.x) + 1.0f),   \
                     __builtin_amdgcn_rcpf(__builtin_amdgcn_exp2f(u.y) + 1.0f)};  \
        v2 tnS = __builtin_elementwise_fma(G1S[k], r1, B1S[k]);               \
        v2 FvS = SELFN(tnS, tnS * leak);                                      \
        ZA[k] += FvS;                                                         \
        v2 r2 = (v2){__builtin_amdgcn_rcpf(__builtin_amdgcn_exp2f(ZA[k].x) + 1.0f), \
                     __builtin_amdgcn_rcpf(__builtin_amdgcn_exp2f(ZA[k].y) + 1.0f)}; \
        CXI[k] = __builtin_elementwise_fma(G2c[k], r2, CXI[k] + B2c[k]);      \
    }

#define STEP_LOOP(SELFN)                                                      \
    for (int j = 0; j < GROUP_; ++j) {                                        \
        const int p = j & 1;                                                  \
        v2 xjA[4], xjB[4];                                                    \
        {                                                                     \
            float4 tA = *(const float4*)&s_xj[0][p][d0];                      \
            float4 tB = *(const float4*)&s_xj[0][p][d0 + 4];                  \
            xjA[0] = (v2){tA.x, tA.y}; xjA[1] = (v2){tA.z, tA.w};             \
            xjA[2] = (v2){tB.x, tB.y}; xjA[3] = (v2){tB.z, tB.w};             \
            float4 uA = *(const float4*)&s_xj[1][p][d0];                      \
            float4 uB = *(const float4*)&s_xj[1][p][d0 + 4];                  \
            xjB[0] = (v2){uA.x, uA.y}; xjB[1] = (v2){uA.z, uA.w};             \
            xjB[2] = (v2){uB.x, uB.y}; xjB[3] = (v2){uB.z, uB.w};             \
        }                                                                     \
        v2 svA = (v2){0.0f, 0.0f}, svB = (v2){0.0f, 0.0f};                    \
        _Pragma("unroll")                                                     \
        for (int k = 0; k < 4; ++k) {                                         \
            svA = __builtin_elementwise_fma(cxiA[k], Wi[k], svA);             \
            svB = __builtin_elementwise_fma(cxiB[k], Wi[k], svB);             \
        }                                                                     \
        _Pragma("unroll")                                                     \
        for (int k = 0; k < 4; ++k) {                                         \
            svA = __builtin_elementwise_fma(xjA[k], Wj[k], svA);              \
            svB = __builtin_elementwise_fma(xjB[k], Wj[k], svB);              \
        }                                                                     \
        const float simA = row16_sum(svA.x + svA.y);                          \
        const float simB = row16_sum(svB.x + svB.y);                          \
        const v2 simAv = (v2){simA, simA};                                    \
        const v2 simBv = (v2){simB, simB};                                    \
        UPD8(cxiA, zaA, simAv, xjA, SELFN)                                    \
        UPD8(cxiB, zaB, simBv, xjB, SELFN)                                    \
        if (j + 1 < GROUP_ && row == j + 1) {                                 \
            float4 oA = {cxiA[0].x, cxiA[0].y, cxiA[1].x, cxiA[1].y};         \
            float4 oB = {cxiA[2].x, cxiA[2].y, cxiA[3].x, cxiA[3].y};         \
            *(float4*)&s_xj[0][p ^ 1][d0]     = oA;                           \
            *(float4*)&s_xj[0][p ^ 1][d0 + 4] = oB;                           \
            float4 qA = {cxiB[0].x, cxiB[0].y, cxiB[1].x, cxiB[1].y};         \
            float4 qB = {cxiB[2].x, cxiB[2].y, cxiB[3].x, cxiB[3].y};         \
            *(float4*)&s_xj[1][p ^ 1][d0]     = qA;                           \
            *(float4*)&s_xj[1][p ^ 1][d0 + 4] = qB;                           \
        }                                                                     \
        LGKM_BARRIER();                                                       \
    }

__global__ __launch_bounds__(256)
__attribute__((amdgpu_waves_per_eu(4, 4)))
void ncn_kernel(
    const float* __restrict__ x,       // (B, L, D)
    const int*   __restrict__ gt,      // (B, L) permutation
    const int*   __restrict__ ctxlens, // (B,)
    const float* __restrict__ W,       // (2D,)
    const float* __restrict__ nalpha,  // (2,)
    const float* __restrict__ ngamma,  // (2D,)
    const float* __restrict__ nbeta,   // (2D,)
    float* __restrict__ out)           // (2, B, L, D) concat: yi_out, ya_out
{
    const int blk = blockIdx.x;
    const int b   = blk >> 6;          // / (NG_/2)
    const int gp  = blk & 63;          // group pair
    const int gA  = gp << 1;
    const int tid = threadIdx.x;
    const int row = tid >> 4;          // 0..15 (token within group)
    const int rl  = tid & 15;          // 0..15 (lane within row)
    const int d0  = rl << 3;           // 8 d-elements per thread

    __shared__ float s_xj[2][2][D_];   // [group][buf][dim] broadcast rows

    const float a1 = nalpha[0];
    const float a2 = nalpha[1];
    const float ca = -a1 * LOG2E_;        // u = ca*(xi + sim*xj); ALPHA=0.5 folded
    const float S  = -2.0f * a2 * LOG2E_; // za = S*xa, so exp2(za) direct
    const float inv_ca = 1.0f / ca;
    const bool  selMin = (S < 0.0f);      // leaky-relu under sign flip

    // Shared per-chunk constants (used by BOTH groups, reused 16x).
    // Wi,Wj pre-scaled by 1/ca; G2c,B2c pre-scaled by ca.
    v2 Wi[4], Wj[4], G1S[4], B1S[4], G2c[4], B2c[4];
    {
        float4 wA = *(const float4*)(W + d0);
        float4 wB = *(const float4*)(W + d0 + 4);
        float4 vA = *(const float4*)(W + D_ + d0);
        float4 vB = *(const float4*)(W + D_ + d0 + 4);
        Wi[0] = inv_ca * (v2){wA.x, wA.y}; Wi[1] = inv_ca * (v2){wA.z, wA.w};
        Wi[2] = inv_ca * (v2){wB.x, wB.y}; Wi[3] = inv_ca * (v2){wB.z, wB.w};
        Wj[0] = inv_ca * (v2){vA.x, vA.y}; Wj[1] = inv_ca * (v2){vA.z, vA.w};
        Wj[2] = inv_ca * (v2){vB.x, vB.y}; Wj[3] = inv_ca * (v2){vB.z, vB.w};

        float4 g1A = *(const float4*)(ngamma + d0);
        float4 g1B = *(const float4*)(ngamma + d0 + 4);
        float4 g2A = *(const float4*)(ngamma + D_ + d0);
        float4 g2B = *(const float4*)(ngamma + D_ + d0 + 4);
        float4 b1A = *(const float4*)(nbeta + d0);
        float4 b1B = *(const float4*)(nbeta + d0 + 4);
        float4 b2A = *(const float4*)(nbeta + D_ + d0);
        float4 b2B = *(const float4*)(nbeta + D_ + d0 + 4);

        v2 g1v[4] = {(v2){g1A.x,g1A.y},(v2){g1A.z,g1A.w},(v2){g1B.x,g1B.y},(v2){g1B.z,g1B.w}};
        v2 b1v[4] = {(v2){b1A.x,b1A.y},(v2){b1A.z,b1A.w},(v2){b1B.x,b1B.y},(v2){b1B.z,b1B.w}};
        v2 g2v[4] = {(v2){g2A.x,g2A.y},(v2){g2A.z,g2A.w},(v2){g2B.x,g2B.y},(v2){g2B.z,g2B.w}};
        v2 b2v[4] = {(v2){b2A.x,b2A.y},(v2){b2A.z,b2A.w},(v2){b2B.x,b2B.y},(v2){b2B.z,b2B.w}};
#pragma unroll
        for (int k = 0; k < 4; ++k) {
            G1S[k] = (S * 2.0f) * g1v[k];        // S*(2*g1)
            B1S[k] = S * (b1v[k] - g1v[k]);      // S*(b1-g1)
            G2c[k] = (ca * 2.0f) * g2v[k];       // ca*(2*g2)
            B2c[k] = ca * (b2v[k] - g2v[k]);     // ca*(b2-g2)
        }
    }

    // Tokens + gather for this row in BOTH groups; state cxi = ca * xi.
    const int lA   = gA * GROUP_ + row;           // group A row
    const int tokA = gt[b * L_ + lA];
    const int tokB = gt[b * L_ + lA + GROUP_];    // group B = gA+1, same row
    const float* xpA = x + ((size_t)(b * L_ + tokA)) * D_ + d0;
    const float* xpB = x + ((size_t)(b * L_ + tokB)) * D_ + d0;

    v2 cxiA[4], zaA[4], cxiB[4], zaB[4];
    {
        const v2 cav = (v2){ca, ca};
        float4 xA = *(const float4*)xpA;
        float4 xB = *(const float4*)(xpA + 4);
        cxiA[0] = cav * (v2){xA.x, xA.y}; cxiA[1] = cav * (v2){xA.z, xA.w};
        cxiA[2] = cav * (v2){xB.x, xB.y}; cxiA[3] = cav * (v2){xB.z, xB.w};
        float4 yA = *(const float4*)xpB;
        float4 yB = *(const float4*)(xpB + 4);
        cxiB[0] = cav * (v2){yA.x, yA.y}; cxiB[1] = cav * (v2){yA.z, yA.w};
        cxiB[2] = cav * (v2){yB.x, yB.y}; cxiB[3] = cav * (v2){yB.z, yB.w};
    }
#pragma unroll
    for (int k = 0; k < 4; ++k) { zaA[k] = (v2){0.0f, 0.0f}; zaB[k] = (v2){0.0f, 0.0f}; }

    // Row 0 publishes both groups' initial cxi into buffer 0
    if (row == 0) {
        float4 oA = {cxiA[0].x, cxiA[0].y, cxiA[1].x, cxiA[1].y};
        float4 oB = {cxiA[2].x, cxiA[2].y, cxiA[3].x, cxiA[3].y};
        *(float4*)&s_xj[0][0][d0]     = oA;
        *(float4*)&s_xj[0][0][d0 + 4] = oB;
        float4 qA = {cxiB[0].x, cxiB[0].y, cxiB[1].x, cxiB[1].y};
        float4 qB = {cxiB[2].x, cxiB[2].y, cxiB[3].x, cxiB[3].y};
        *(float4*)&s_xj[1][0][d0]     = qA;
        *(float4*)&s_xj[1][0][d0 + 4] = qB;
    }
    __syncthreads();

    const v2 leak = (v2){0.01f, 0.01f};

    // Uniform split: one v_pk_min / v_pk_max per elem.
    if (selMin) {
        STEP_LOOP(__builtin_elementwise_min)
    } else {
        STEP_LOOP(__builtin_elementwise_max)
    }

    // Recover xi = cxi / ca and xa = za / S; fold validity into the unscale.
    const float invS = 1.0f / S;
    const int   cl   = ctxlens[b];
    const bool  validA = (gA * GROUP_) < cl;
    const bool  validB = ((gA + 1) * GROUP_) < cl;
    const float mAc = validA ? inv_ca : 0.0f;
    const float mAs = validA ? invS   : 0.0f;
    const float mBc = validB ? inv_ca : 0.0f;
    const float mBs = validB ? invS   : 0.0f;
    const v2 mAcv = (v2){mAc, mAc}, mAsv = (v2){mAs, mAs};
    const v2 mBcv = (v2){mBc, mBc}, mBsv = (v2){mBs, mBs};

    float* o1A = out + ((size_t)(b * L_ + tokA)) * D_ + d0;
    float* o1B = out + ((size_t)(b * L_ + tokB)) * D_ + d0;
    float* o2A = o1A + (size_t)B_ * L_ * D_;
    float* o2B = o1B + (size_t)B_ * L_ * D_;

    v2 y0 = cxiA[0] * mAcv, y1 = cxiA[1] * mAcv, y2 = cxiA[2] * mAcv, y3 = cxiA[3] * mAcv;
    v2 z0 = zaA[0] * mAsv,  z1 = zaA[1] * mAsv,  z2 = zaA[2] * mAsv,  z3 = zaA[3] * mAsv;
    float4 s1A = {y0.x, y0.y, y1.x, y1.y};
    float4 s1B = {y2.x, y2.y, y3.x, y3.y};
    float4 s2A = {z0.x, z0.y, z1.x, z1.y};
    float4 s2B = {z2.x, z2.y, z3.x, z3.y};
    *(float4*)o1A       = s1A;
    *(float4*)(o1A + 4) = s1B;
    *(float4*)o2A       = s2A;
    *(float4*)(o2A + 4) = s2B;

    v2 w0 = cxiB[0] * mBcv, w1 = cxiB[1] * mBcv, w2 = cxiB[2] * mBcv, w3 = cxiB[3] * mBcv;
    v2 v0 = zaB[0] * mBsv,  v1 = zaB[1] * mBsv,  v2_ = zaB[2] * mBsv, v3 = zaB[3] * mBsv;
    float4 t1A = {w0.x, w0.y, w1.x, w1.y};
    float4 t1B = {w2.x, w2.y, w3.x, w3.y};
    float4 t2A = {v0.x, v0.y, v1.x, v1.y};
    float4 t2B = {v2_.x, v2_.y, v3.x, v3.y};
    *(float4*)o1B       = t1A;
    *(float4*)(o1B + 4) = t1B;
    *(float4*)o2B       = t2A;
    *(float4*)(o2B + 4) = t2B;
}

extern "C" void kernel_launch(void* const* d_in, const int* in_sizes, int n_in,
                              void* d_out, int out_size, void* d_ws, size_t ws_size,
                              hipStream_t stream) {
    const float* x  = (const float*)d_in[0];
    const int*   gt = (const int*)d_in[1];
    const int*   cl = (const int*)d_in[2];
    const float* W  = (const float*)d_in[3];
    const float* na = (const float*)d_in[4];
    const float* ng = (const float*)d_in[5];
    const float* nb = (const float*)d_in[6];
    float* out = (float*)d_out;

    ncn_kernel<<<B_ * (NG_ / 2), 256, 0, stream>>>(x, gt, cl, W, na, ng, nb, out);
}